// Round 13
// baseline (311.371 us; speedup 1.0000x reference)
//
#include <hip/hip_runtime.h>
#include <math.h>

#define MTOT 8192   // B*N
#define HD   512    // hidden dim

typedef __attribute__((ext_vector_type(8))) short bf16x8;
typedef __attribute__((ext_vector_type(4))) float floatx4;

__device__ inline unsigned short f2bf(float f) {
    unsigned int u = __float_as_uint(f);
    unsigned int r = (u + 0x7FFFu + ((u >> 16) & 1u)) >> 16;
    return (unsigned short)r;
}
__device__ inline float bf2f(unsigned short h) {
    return __uint_as_float(((unsigned int)h) << 16);
}

// wave-wide sum: 4 DPP row_ror adds (VALU pipe, row=16 lanes) + 2 shfl_xor
// (LDS pipe) for the cross-row levels. Replaces 6 dependent ds_bpermute.
__device__ inline float wave_sum64(float v) {
    int t;
    t = __builtin_amdgcn_update_dpp(0, __float_as_int(v), 0x121, 0xF, 0xF, true); v += __int_as_float(t); // row_ror:1
    t = __builtin_amdgcn_update_dpp(0, __float_as_int(v), 0x122, 0xF, 0xF, true); v += __int_as_float(t); // row_ror:2
    t = __builtin_amdgcn_update_dpp(0, __float_as_int(v), 0x124, 0xF, 0xF, true); v += __int_as_float(t); // row_ror:4
    t = __builtin_amdgcn_update_dpp(0, __float_as_int(v), 0x128, 0xF, 0xF, true); v += __int_as_float(t); // row_ror:8
    v += __shfl_xor(v, 16, 64);
    v += __shfl_xor(v, 32, 64);
    return v;
}

// ---------------- CSR build (separate dispatches — r8: fusing count into the
// GEMM cost +9us via L2 atomic contention; r7: no nt hints on latency-critical
// loads (+9us); no grid.sync re-fusion (~35us each, prior session).

__global__ void count_deg(const int* __restrict__ dst, int* __restrict__ deg, int E) {
    int i = blockIdx.x * 256 + threadIdx.x;
    if (i < E) atomicAdd(&deg[dst[i]], 1);
}

__global__ __launch_bounds__(1024) void scan_offsets(const int* __restrict__ deg,
                                                     int* __restrict__ offs,
                                                     int* __restrict__ cursor) {
    __shared__ int part[1024];
    int tid = threadIdx.x;
    int base = tid * 8;
    int v[8]; int s = 0;
    #pragma unroll
    for (int i = 0; i < 8; ++i) { v[i] = deg[base + i]; s += v[i]; }
    part[tid] = s;
    __syncthreads();
    for (int off = 1; off < 1024; off <<= 1) {
        int t = (tid >= off) ? part[tid - off] : 0;
        __syncthreads();
        part[tid] += t;
        __syncthreads();
    }
    int run = (tid == 0) ? 0 : part[tid - 1];
    #pragma unroll
    for (int i = 0; i < 8; ++i) {
        offs[base + i] = run;
        cursor[base + i] = run;
        run += v[i];
    }
    if (tid == 1023) offs[MTOT] = run;
}

__global__ void scatter_edges(const int* __restrict__ src, const int* __restrict__ dst,
                              int* __restrict__ cursor, int* __restrict__ csr_src, int E) {
    int i = blockIdx.x * 256 + threadIdx.x;
    if (i < E) {
        int p = atomicAdd(&cursor[dst[i]], 1);
        csr_src[p] = src[i];
    }
}

// ---------------- combined weight + activation split + deg zero ----------------
// z in [0,6): weight matrix z. z == 6: activation split. z == 7: zero deg.

__global__ __launch_bounds__(256) void prep_convert(
    const float* __restrict__ W0, const float* __restrict__ W1,
    const float* __restrict__ W2, const float* __restrict__ W3,
    const float* __restrict__ W4, const float* __restrict__ W5,
    unsigned short* __restrict__ wtbase,
    const float* __restrict__ X,
    unsigned short* __restrict__ Ahi, unsigned short* __restrict__ Alo,
    int* __restrict__ deg)
{
    int z = blockIdx.z;
    if (z == 7) {
        if (blockIdx.x == 0 && blockIdx.y == 0)
            for (int i = threadIdx.x; i < MTOT; i += 256) deg[i] = 0;
        return;
    }
    if (z == 6) {
        int bid = blockIdx.x * 16 + blockIdx.y;       // 0..255
        int t0 = bid * 256 + threadIdx.x;             // 0..65535
        #pragma unroll
        for (int it = 0; it < 16; ++it) {
            int i = (t0 + it * 65536) * 4;
            float4 vv = *(const float4*)(X + i);
            ushort4 h, l;
            h.x = f2bf(vv.x); l.x = f2bf(vv.x - bf2f(h.x));
            h.y = f2bf(vv.y); l.y = f2bf(vv.y - bf2f(h.y));
            h.z = f2bf(vv.z); l.z = f2bf(vv.z - bf2f(h.z));
            h.w = f2bf(vv.w); l.w = f2bf(vv.w - bf2f(h.w));
            *(ushort4*)(Ahi + i) = h;
            *(ushort4*)(Alo + i) = l;
        }
        return;
    }
    const float* W = (z == 0) ? W0 : (z == 1) ? W1 : (z == 2) ? W2
                   : (z == 3) ? W3 : (z == 4) ? W4 : W5;
    int L = z >> 1, lr = z & 1;
    const size_t SZ = (size_t)HD * HD;
    unsigned short* Whi = wtbase + (L * 4 + lr * 2) * SZ;
    unsigned short* Wlo = Whi + SZ;

    __shared__ float t[32][33];
    int bx = blockIdx.x * 32;  // n base
    int by = blockIdx.y * 32;  // k base
    int tx = threadIdx.x & 31, ty = threadIdx.x >> 5;
    for (int i = ty; i < 32; i += 8)
        t[i][tx] = W[(size_t)(by + i) * HD + bx + tx];
    __syncthreads();
    for (int i = ty; i < 32; i += 8) {
        float vv = t[tx][i];
        unsigned short h = f2bf(vv);
        unsigned short l = f2bf(vv - bf2f(h));
        Whi[(size_t)(bx + i) * HD + by + tx] = h;
        Wlo[(size_t)(bx + i) * HD + by + tx] = l;
    }
}

// ---------------- split-bf16 MFMA dual GEMM, 128x128 + swizzle + DBUF (r12 best) ----------------
// GEMM moratorium: r5 (traffic), r11 (occupancy), r12 (dbuf) all landed within
// noise at ~40us — counters (MfmaUtil 23, VALU 17, HBM 17, conflicts small)
// show no single pipe saturated and the grid caps co-residency at 2 blocks/CU.
// Keep this measured-best form; do not edit without a new counter signal.

__global__ __launch_bounds__(256) void gemm_mfma_dual(
    const unsigned short* __restrict__ Ahi, const unsigned short* __restrict__ Alo,
    const unsigned short* __restrict__ Bhi_l, const unsigned short* __restrict__ Blo_l,
    const unsigned short* __restrict__ Bhi_r, const unsigned short* __restrict__ Blo_r,
    const float* __restrict__ bias_l, const float* __restrict__ bias_r,
    float* __restrict__ Cl, float* __restrict__ Cr)
{
    int bid = blockIdx.x;
    int virt = (bid & 7) * 64 + (bid >> 3);   // bijective: 512 % 8 == 0
    int g  = virt >> 3;        // 0..63  -> bm group (A-panel); 8 per XCD
    int q  = virt & 7;         // 8 sharers of this panel
    int bz = q >> 2;           // 0..1   -> l/r
    int bm = g * 128, bn = (q & 3) * 128;

    const unsigned short* Bhi = bz ? Bhi_r : Bhi_l;
    const unsigned short* Blo = bz ? Blo_r : Blo_l;
    const float* bias         = bz ? bias_r : bias_l;
    float* C                  = bz ? Cr : Cl;

    __shared__ __align__(16) unsigned short lds[2][4 * 128 * 32];   // 2 x 32KB

    int tid = threadIdx.x;
    int wave = tid >> 6, lane = tid & 63;

    const unsigned short* gsrc[4] = {Ahi, Alo, Bhi, Blo};
    int rowbase[4] = {bm, bm, bn, bn};

    const unsigned short* gbase =
        gsrc[wave] + (size_t)(rowbase[wave] + (lane >> 2)) * 512 + (lane & 3) * 8;

    floatx4 acc[4][4] = {};

    int wm = wave & 1, wn = wave >> 1;
    int lr = lane & 15, lq = lane >> 4;

    #pragma unroll
    for (int rg = 0; rg < 8; ++rg) {
        __builtin_amdgcn_global_load_lds(
            (const __attribute__((address_space(1))) unsigned int*)(gbase + (size_t)rg * 16 * 512),
            (__attribute__((address_space(3))) unsigned int*)(&lds[0][wave * 4096 + rg * 512]),
            16, 0, 0);
    }
    __syncthreads();

    for (int it = 0; it < 16; ++it) {
        int cur = it & 1;
        if (it < 15) {
            const unsigned short* g2 = gbase + (it + 1) * 32;
            #pragma unroll
            for (int rg = 0; rg < 8; ++rg) {
                __builtin_amdgcn_global_load_lds(
                    (const __attribute__((address_space(1))) unsigned int*)(g2 + (size_t)rg * 16 * 512),
                    (__attribute__((address_space(3))) unsigned int*)(&lds[cur ^ 1][wave * 4096 + rg * 512]),
                    16, 0, 0);
            }
        }

        bf16x8 ah[4], al[4], bh[4], bl_[4];
        #pragma unroll
        for (int i = 0; i < 4; ++i) {
            int mrow = wm * 64 + i * 16 + lr;
            ah[i]  = *(const bf16x8*)&lds[cur][0 * 4096 + mrow * 32 + lq * 8];
            al[i]  = *(const bf16x8*)&lds[cur][1 * 4096 + mrow * 32 + lq * 8];
            int nrow = wn * 64 + i * 16 + lr;
            bh[i]  = *(const bf16x8*)&lds[cur][2 * 4096 + nrow * 32 + lq * 8];
            bl_[i] = *(const bf16x8*)&lds[cur][3 * 4096 + nrow * 32 + lq * 8];
        }
        #pragma unroll
        for (int i = 0; i < 4; ++i)
            #pragma unroll
            for (int j = 0; j < 4; ++j) {
                acc[i][j] = __builtin_amdgcn_mfma_f32_16x16x32_bf16(ah[i], bh[j],  acc[i][j], 0, 0, 0);
                acc[i][j] = __builtin_amdgcn_mfma_f32_16x16x32_bf16(ah[i], bl_[j], acc[i][j], 0, 0, 0);
                acc[i][j] = __builtin_amdgcn_mfma_f32_16x16x32_bf16(al[i], bh[j],  acc[i][j], 0, 0, 0);
            }

        __syncthreads();
    }

    #pragma unroll
    for (int j = 0; j < 4; ++j) {
        int n = bn + wn * 64 + j * 16 + lr;
        float bv = bias[n];
        #pragma unroll
        for (int i = 0; i < 4; ++i) {
            int mbase = bm + wm * 64 + i * 16 + lq * 4;
            #pragma unroll
            for (int r = 0; r < 4; ++r)
                C[(size_t)(mbase + r) * 512 + n] = acc[i][j][r] + bv;
        }
    }
}

// ---------------- online-softmax aggregation v10: 2 nodes per wave, phase-interleaved ----------------
// r9: in-wave load pipelining -6us; r10: cross-wave split-merge NET-NEGATIVE.
// Remaining chain: the loop-carried softmax dependency (batch-max -> rescale ->
// exp -> acc) serializes consecutive stages. v10 interleaves TWO nodes' stages
// in one wave: consecutive PROCESS phases are independent (private m/s/acc),
// each node single-buffered (issue-after-consume, window = one full phase),
// idx prefetched one phase ahead. No merge, no barrier, no duplicated stage
// buffers (+~35 VGPR for node1 state only; launch_bounds(256,3) to avoid
// spill: 3 waves/SIMD x 2 chains = 6 chains/SIMD vs v8's 4).
// Numerics: per-edge math and 4-edge batch grouping identical to v8.

#define DOT8P(Xa, Xb, Ra, Rb, d0, d1)                                     \
    {                                                                     \
        float t_;                                                         \
        t_ = Xa.x + Ra.x; d0 = fmaf(av0.x, t_, d0); d1 = fmaf(av0.x, fabsf(t_), d1); \
        t_ = Xa.y + Ra.y; d0 = fmaf(av0.y, t_, d0); d1 = fmaf(av0.y, fabsf(t_), d1); \
        t_ = Xa.z + Ra.z; d0 = fmaf(av0.z, t_, d0); d1 = fmaf(av0.z, fabsf(t_), d1); \
        t_ = Xa.w + Ra.w; d0 = fmaf(av0.w, t_, d0); d1 = fmaf(av0.w, fabsf(t_), d1); \
        t_ = Xb.x + Rb.x; d0 = fmaf(av1.x, t_, d0); d1 = fmaf(av1.x, fabsf(t_), d1); \
        t_ = Xb.y + Rb.y; d0 = fmaf(av1.y, t_, d0); d1 = fmaf(av1.y, fabsf(t_), d1); \
        t_ = Xb.z + Rb.z; d0 = fmaf(av1.z, t_, d0); d1 = fmaf(av1.z, fabsf(t_), d1); \
        t_ = Xb.w + Rb.w; d0 = fmaf(av1.w, t_, d0); d1 = fmaf(av1.w, fabsf(t_), d1); \
    }

#define PROC4(Xa, Xb, q, NE, M, S, A0, A1, Ra, Rb)                        \
    {                                                                     \
        float pe[4];                                                      \
        _Pragma("unroll")                                                 \
        for (int k2 = 0; k2 < 4; ++k2) {                                  \
            float d0 = 0.f, d1 = 0.f;                                     \
            DOT8P(Xa[k2], Xb[k2], Ra, Rb, d0, d1);                        \
            pe[k2] = fmaf(0.6f, d0, 0.4f * d1);                           \
        }                                                                 \
        _Pragma("unroll")                                                 \
        for (int k2 = 0; k2 < 4; ++k2) pe[k2] = wave_sum64(pe[k2]);       \
        float e0 = pe[0];                                                 \
        float e1 = ((q) + 1 < (NE)) ? pe[1] : -3.0e38f;                   \
        float e2 = ((q) + 2 < (NE)) ? pe[2] : -3.0e38f;                   \
        float e3 = ((q) + 3 < (NE)) ? pe[3] : -3.0e38f;                   \
        float bm4 = fmaxf(fmaxf(e0, e1), fmaxf(e2, e3));                  \
        if (bm4 > (M)) {                                                  \
            float sc = __expf((M) - bm4);                                 \
            (S) *= sc;                                                    \
            A0.x *= sc; A0.y *= sc; A0.z *= sc; A0.w *= sc;               \
            A1.x *= sc; A1.y *= sc; A1.z *= sc; A1.w *= sc;               \
            (M) = bm4;                                                    \
        }                                                                 \
        float w0 = __expf(e0 - (M)), w1 = __expf(e1 - (M));               \
        float w2 = __expf(e2 - (M)), w3 = __expf(e3 - (M));               \
        (S) += (w0 + w1) + (w2 + w3);                                     \
        A0.x = fmaf(w0, Xa[0].x, fmaf(w1, Xa[1].x, fmaf(w2, Xa[2].x, fmaf(w3, Xa[3].x, A0.x)))); \
        A0.y = fmaf(w0, Xa[0].y, fmaf(w1, Xa[1].y, fmaf(w2, Xa[2].y, fmaf(w3, Xa[3].y, A0.y)))); \
        A0.z = fmaf(w0, Xa[0].z, fmaf(w1, Xa[1].z, fmaf(w2, Xa[2].z, fmaf(w3, Xa[3].z, A0.z)))); \
        A0.w = fmaf(w0, Xa[0].w, fmaf(w1, Xa[1].w, fmaf(w2, Xa[2].w, fmaf(w3, Xa[3].w, A0.w)))); \
        A1.x = fmaf(w0, Xb[0].x, fmaf(w1, Xb[1].x, fmaf(w2, Xb[2].x, fmaf(w3, Xb[3].x, A1.x)))); \
        A1.y = fmaf(w0, Xb[0].y, fmaf(w1, Xb[1].y, fmaf(w2, Xb[2].y, fmaf(w3, Xb[3].y, A1.y)))); \
        A1.z = fmaf(w0, Xb[0].z, fmaf(w1, Xb[1].z, fmaf(w2, Xb[2].z, fmaf(w3, Xb[3].z, A1.z)))); \
        A1.w = fmaf(w0, Xb[0].w, fmaf(w1, Xb[1].w, fmaf(w2, Xb[2].w, fmaf(w3, Xb[3].w, A1.w)))); \
    }

#define STORE_NODE(ROWOFF, A0, A1, S)                                     \
    {                                                                     \
        float inv = ((S) > 0.f) ? 1.f / (S) : 0.f;                        \
        float4 o0, o1;                                                    \
        o0.x = fmaf(A0.x, inv, b0.x); o0.y = fmaf(A0.y, inv, b0.y);       \
        o0.z = fmaf(A0.z, inv, b0.z); o0.w = fmaf(A0.w, inv, b0.w);       \
        o1.x = fmaf(A1.x, inv, b1.x); o1.y = fmaf(A1.y, inv, b1.y);       \
        o1.z = fmaf(A1.z, inv, b1.z); o1.w = fmaf(A1.w, inv, b1.w);       \
        if (write_fp32) {                                                 \
            *(float4*)(out + (ROWOFF)) = o0;                              \
            *(float4*)(out + (ROWOFF) + 4) = o1;                          \
        } else {                                                          \
            ushort4 h, lo;                                                \
            h.x = f2bf(o0.x); lo.x = f2bf(o0.x - bf2f(h.x));              \
            h.y = f2bf(o0.y); lo.y = f2bf(o0.y - bf2f(h.y));              \
            h.z = f2bf(o0.z); lo.z = f2bf(o0.z - bf2f(h.z));              \
            h.w = f2bf(o0.w); lo.w = f2bf(o0.w - bf2f(h.w));              \
            *(ushort4*)(Ohi + (ROWOFF)) = h;                              \
            *(ushort4*)(Olo + (ROWOFF)) = lo;                             \
            h.x = f2bf(o1.x); lo.x = f2bf(o1.x - bf2f(h.x));              \
            h.y = f2bf(o1.y); lo.y = f2bf(o1.y - bf2f(h.y));              \
            h.z = f2bf(o1.z); lo.z = f2bf(o1.z - bf2f(h.z));              \
            h.w = f2bf(o1.w); lo.w = f2bf(o1.w - bf2f(h.w));              \
            *(ushort4*)(Ohi + (ROWOFF) + 4) = h;                          \
            *(ushort4*)(Olo + (ROWOFF) + 4) = lo;                         \
        }                                                                 \
    }

__global__ __launch_bounds__(256, 3) void gat_online(
    const float* __restrict__ xl, const float* __restrict__ xr,
    const float* __restrict__ avec, const float* __restrict__ bias,
    const int* __restrict__ offs, const int* __restrict__ csr_src,
    float* __restrict__ out, unsigned short* __restrict__ Ohi,
    unsigned short* __restrict__ Olo, int write_fp32)
{
    int gid = blockIdx.x;     // 1024 blocks: 8 nodes per block (4 waves x 2)
    int wv = threadIdx.x >> 6, lane = threadIdx.x & 63;
    int n0 = ((gid & 7) << 10) + ((gid >> 3) << 3) + wv * 2;
    int n1 = n0 + 1;

    int nb0 = offs[n0], ne0 = offs[n0 + 1];
    int nb1 = offs[n1], ne1 = offs[n1 + 1];

    // stage0 indices (clamped) for both nodes
    int j0c = (nb0 < ne0) ? csr_src[nb0] : 0;
    int j1c = (nb1 < ne1) ? csr_src[nb1] : 0;
    int i0[4], i1[4];
    i0[0] = j0c; i1[0] = j1c;
    #pragma unroll
    for (int k = 1; k < 4; ++k) {
        i0[k] = (nb0 + k < ne0) ? csr_src[nb0 + k] : j0c;
        i1[k] = (nb1 + k < ne1) ? csr_src[nb1 + k] : j1c;
    }

    size_t loff = (size_t)lane * 8;
    size_t row0 = (size_t)n0 * HD + loff;
    size_t row1 = (size_t)n1 * HD + loff;
    float4 r0a = *(const float4*)(xr + row0);
    float4 r0b = *(const float4*)(xr + row0 + 4);
    float4 r1a = *(const float4*)(xr + row1);
    float4 r1b = *(const float4*)(xr + row1 + 4);
    float4 av0 = *(const float4*)(avec + loff);
    float4 av1 = *(const float4*)(avec + loff + 4);

    // stage0 data issue for both nodes (16 loads in flight)
    float4 X0a[4], X0b[4], X1a[4], X1b[4];
    #pragma unroll
    for (int k = 0; k < 4; ++k) {
        const float* xp = xl + (size_t)i0[k] * HD + loff;
        X0a[k] = *(const float4*)xp;
        X0b[k] = *(const float4*)(xp + 4);
    }
    #pragma unroll
    for (int k = 0; k < 4; ++k) {
        const float* xp = xl + (size_t)i1[k] * HD + loff;
        X1a[k] = *(const float4*)xp;
        X1b[k] = *(const float4*)(xp + 4);
    }

    // idx prefetch, one phase ahead
    int jn0[4], jn1[4];
    #pragma unroll
    for (int k = 0; k < 4; ++k) {
        jn0[k] = (nb0 + 4 + k < ne0) ? csr_src[nb0 + 4 + k] : j0c;
        jn1[k] = (nb1 + 4 + k < ne1) ? csr_src[nb1 + 4 + k] : j1c;
    }

    float m0 = -3.0e38f, s0 = 0.f, m1 = -3.0e38f, s1 = 0.f;
    float4 a00 = {0,0,0,0}, a01 = {0,0,0,0};
    float4 a10 = {0,0,0,0}, a11 = {0,0,0,0};

    int p0 = nb0, p1 = nb1;
    while (p0 < ne0 || p1 < ne1) {
        if (p0 < ne0) {                 // phase: node0 (wave-uniform branch)
            PROC4(X0a, X0b, p0, ne0, m0, s0, a00, a01, r0a, r0b);
            p0 += 4;
            if (p0 < ne0) {             // refill buffer + prefetch next idx
                #pragma unroll
                for (int k = 0; k < 4; ++k) {
                    const float* xp = xl + (size_t)jn0[k] * HD + loff;
                    X0a[k] = *(const float4*)xp;
                    X0b[k] = *(const float4*)(xp + 4);
                }
                int p2 = p0 + 4;
                #pragma unroll
                for (int k = 0; k < 4; ++k)
                    jn0[k] = (p2 + k < ne0) ? csr_src[p2 + k] : j0c;
            }
        }
        if (p1 < ne1) {                 // phase: node1 — independent chain
            PROC4(X1a, X1b, p1, ne1, m1, s1, a10, a11, r1a, r1b);
            p1 += 4;
            if (p1 < ne1) {
                #pragma unroll
                for (int k = 0; k < 4; ++k) {
                    const float* xp = xl + (size_t)jn1[k] * HD + loff;
                    X1a[k] = *(const float4*)xp;
                    X1b[k] = *(const float4*)(xp + 4);
                }
                int p2 = p1 + 4;
                #pragma unroll
                for (int k = 0; k < 4; ++k)
                    jn1[k] = (p2 + k < ne1) ? csr_src[p2 + k] : j1c;
            }
        }
    }

    float4 b0 = *(const float4*)(bias + loff);
    float4 b1 = *(const float4*)(bias + loff + 4);
    STORE_NODE(row0, a00, a01, s0);
    STORE_NODE(row1, a10, a11, s1);
}

// ---------------- launch ----------------

extern "C" void kernel_launch(void* const* d_in, const int* in_sizes, int n_in,
                              void* d_out, int out_size, void* d_ws, size_t ws_size,
                              hipStream_t stream) {
    const float* x0 = (const float*)d_in[0];
    const int* eidx = (const int*)d_in[2];
    int E = in_sizes[2] / 2;
    const int* esrc = eidx;
    const int* edst = eidx + E;

    const float* Wl[3] = {(const float*)d_in[3],  (const float*)d_in[9],  (const float*)d_in[15]};
    const float* bl[3] = {(const float*)d_in[4],  (const float*)d_in[10], (const float*)d_in[16]};
    const float* Wr[3] = {(const float*)d_in[5],  (const float*)d_in[11], (const float*)d_in[17]};
    const float* br[3] = {(const float*)d_in[6],  (const float*)d_in[12], (const float*)d_in[18]};
    const float* av[3] = {(const float*)d_in[7],  (const float*)d_in[13], (const float*)d_in[19]};
    const float* bs[3] = {(const float*)d_in[8],  (const float*)d_in[14], (const float*)d_in[20]};

    char* w = (char*)d_ws;
    unsigned short* Ahi = (unsigned short*)w; w += (size_t)MTOT * HD * 2;
    unsigned short* Alo = (unsigned short*)w; w += (size_t)MTOT * HD * 2;
    unsigned short* wtbase = (unsigned short*)w; w += 12 * (size_t)HD * HD * 2;
    float* xl = (float*)w; w += (size_t)MTOT * HD * 4;
    float* xr = (float*)w; w += (size_t)MTOT * HD * 4;
    int* deg    = (int*)w;
    int* offs   = deg + MTOT;
    int* cursor = offs + MTOT + 8;
    int* csr    = cursor + MTOT;
    const size_t SZ = (size_t)HD * HD;

    prep_convert<<<dim3(16, 16, 8), 256, 0, stream>>>(
        Wl[0], Wr[0], Wl[1], Wr[1], Wl[2], Wr[2], wtbase, x0, Ahi, Alo, deg);
    count_deg<<<(E + 255) / 256, 256, 0, stream>>>(edst, deg, E);
    scan_offsets<<<1, 1024, 0, stream>>>(deg, offs, cursor);
    scatter_edges<<<(E + 255) / 256, 256, 0, stream>>>(esrc, edst, cursor, csr, E);

    for (int L = 0; L < 3; ++L) {
        gemm_mfma_dual<<<512, 256, 0, stream>>>(Ahi, Alo,
            wtbase + (L * 4 + 0) * SZ, wtbase + (L * 4 + 1) * SZ,
            wtbase + (L * 4 + 2) * SZ, wtbase + (L * 4 + 3) * SZ,
            bl[L], br[L], xl, xr);
        int last = (L == 2);
        gat_online<<<MTOT / 8, 256, 0, stream>>>(xl, xr, av[L], bs[L], offs, csr,
                                                 last ? (float*)d_out : nullptr,
                                                 last ? nullptr : Ahi,
                                                 last ? nullptr : Alo,
                                                 last);
    }
}

// Round 14
// 301.622 us; speedup vs baseline: 1.0323x; 1.0323x over previous
//
#include <hip/hip_runtime.h>
#include <math.h>

#define MTOT 8192   // B*N
#define HD   512    // hidden dim

typedef __attribute__((ext_vector_type(8))) short bf16x8;
typedef __attribute__((ext_vector_type(4))) float floatx4;
typedef __attribute__((ext_vector_type(4))) float f32x4;
typedef __attribute__((ext_vector_type(4))) unsigned short u16x4;

__device__ inline unsigned short f2bf(float f) {
    unsigned int u = __float_as_uint(f);
    unsigned int r = (u + 0x7FFFu + ((u >> 16) & 1u)) >> 16;
    return (unsigned short)r;
}
__device__ inline float bf2f(unsigned short h) {
    return __uint_as_float(((unsigned int)h) << 16);
}

// non-temporal STORE-ONLY helpers (r13 refinement of r5-H1 with r7's lesson:
// nt on latency-critical LOADS hurt; stores are fire-and-forget, and the
// Ohi/Olo/out write stream is 2MB/XCD of pure L2 pollution competing with
// the 2MB xl gather slice under LRU). ext_vector shims per r6 compile fix.
__device__ inline void nt_st4(float* p, float4 v) {
    f32x4 t = {v.x, v.y, v.z, v.w};
    __builtin_nontemporal_store(t, (f32x4*)p);
}
__device__ inline void nt_stu4(unsigned short* p, ushort4 v) {
    u16x4 t = {v.x, v.y, v.z, v.w};
    __builtin_nontemporal_store(t, (u16x4*)p);
}

// wave-wide sum: 4 DPP row_ror adds (VALU pipe, row=16 lanes) + 2 shfl_xor
// (LDS pipe) for the cross-row levels. Replaces 6 dependent ds_bpermute.
__device__ inline float wave_sum64(float v) {
    int t;
    t = __builtin_amdgcn_update_dpp(0, __float_as_int(v), 0x121, 0xF, 0xF, true); v += __int_as_float(t); // row_ror:1
    t = __builtin_amdgcn_update_dpp(0, __float_as_int(v), 0x122, 0xF, 0xF, true); v += __int_as_float(t); // row_ror:2
    t = __builtin_amdgcn_update_dpp(0, __float_as_int(v), 0x124, 0xF, 0xF, true); v += __int_as_float(t); // row_ror:4
    t = __builtin_amdgcn_update_dpp(0, __float_as_int(v), 0x128, 0xF, 0xF, true); v += __int_as_float(t); // row_ror:8
    v += __shfl_xor(v, 16, 64);
    v += __shfl_xor(v, 32, 64);
    return v;
}

// ---------------- CSR build (separate dispatches — r8: fusing count into the
// GEMM cost +9us via L2 atomic contention; r7: no nt hints on latency-critical
// loads (+9us); no grid.sync re-fusion (~35us each, prior session). Fusing
// count into prep nets zero: deg must be re-zeroed after the harness's
// per-iteration workspace poison, so it would just trade a kernel for a memset.

__global__ void count_deg(const int* __restrict__ dst, int* __restrict__ deg, int E) {
    int i = blockIdx.x * 256 + threadIdx.x;
    if (i < E) atomicAdd(&deg[dst[i]], 1);
}

__global__ __launch_bounds__(1024) void scan_offsets(const int* __restrict__ deg,
                                                     int* __restrict__ offs,
                                                     int* __restrict__ cursor) {
    __shared__ int part[1024];
    int tid = threadIdx.x;
    int base = tid * 8;
    int v[8]; int s = 0;
    #pragma unroll
    for (int i = 0; i < 8; ++i) { v[i] = deg[base + i]; s += v[i]; }
    part[tid] = s;
    __syncthreads();
    for (int off = 1; off < 1024; off <<= 1) {
        int t = (tid >= off) ? part[tid - off] : 0;
        __syncthreads();
        part[tid] += t;
        __syncthreads();
    }
    int run = (tid == 0) ? 0 : part[tid - 1];
    #pragma unroll
    for (int i = 0; i < 8; ++i) {
        offs[base + i] = run;
        cursor[base + i] = run;
        run += v[i];
    }
    if (tid == 1023) offs[MTOT] = run;
}

__global__ void scatter_edges(const int* __restrict__ src, const int* __restrict__ dst,
                              int* __restrict__ cursor, int* __restrict__ csr_src, int E) {
    int i = blockIdx.x * 256 + threadIdx.x;
    if (i < E) {
        int p = atomicAdd(&cursor[dst[i]], 1);
        csr_src[p] = src[i];
    }
}

// ---------------- combined weight + activation split + deg zero ----------------
// z in [0,6): weight matrix z. z == 6: activation split. z == 7: zero deg.

__global__ __launch_bounds__(256) void prep_convert(
    const float* __restrict__ W0, const float* __restrict__ W1,
    const float* __restrict__ W2, const float* __restrict__ W3,
    const float* __restrict__ W4, const float* __restrict__ W5,
    unsigned short* __restrict__ wtbase,
    const float* __restrict__ X,
    unsigned short* __restrict__ Ahi, unsigned short* __restrict__ Alo,
    int* __restrict__ deg)
{
    int z = blockIdx.z;
    if (z == 7) {
        if (blockIdx.x == 0 && blockIdx.y == 0)
            for (int i = threadIdx.x; i < MTOT; i += 256) deg[i] = 0;
        return;
    }
    if (z == 6) {
        int bid = blockIdx.x * 16 + blockIdx.y;       // 0..255
        int t0 = bid * 256 + threadIdx.x;             // 0..65535
        #pragma unroll
        for (int it = 0; it < 16; ++it) {
            int i = (t0 + it * 65536) * 4;
            float4 vv = *(const float4*)(X + i);
            ushort4 h, l;
            h.x = f2bf(vv.x); l.x = f2bf(vv.x - bf2f(h.x));
            h.y = f2bf(vv.y); l.y = f2bf(vv.y - bf2f(h.y));
            h.z = f2bf(vv.z); l.z = f2bf(vv.z - bf2f(h.z));
            h.w = f2bf(vv.w); l.w = f2bf(vv.w - bf2f(h.w));
            *(ushort4*)(Ahi + i) = h;
            *(ushort4*)(Alo + i) = l;
        }
        return;
    }
    const float* W = (z == 0) ? W0 : (z == 1) ? W1 : (z == 2) ? W2
                   : (z == 3) ? W3 : (z == 4) ? W4 : W5;
    int L = z >> 1, lr = z & 1;
    const size_t SZ = (size_t)HD * HD;
    unsigned short* Whi = wtbase + (L * 4 + lr * 2) * SZ;
    unsigned short* Wlo = Whi + SZ;

    __shared__ float t[32][33];
    int bx = blockIdx.x * 32;  // n base
    int by = blockIdx.y * 32;  // k base
    int tx = threadIdx.x & 31, ty = threadIdx.x >> 5;
    for (int i = ty; i < 32; i += 8)
        t[i][tx] = W[(size_t)(by + i) * HD + bx + tx];
    __syncthreads();
    for (int i = ty; i < 32; i += 8) {
        float vv = t[tx][i];
        unsigned short h = f2bf(vv);
        unsigned short l = f2bf(vv - bf2f(h));
        Whi[(size_t)(bx + i) * HD + by + tx] = h;
        Wlo[(size_t)(bx + i) * HD + by + tx] = l;
    }
}

// ---------------- split-bf16 MFMA dual GEMM, 128x128 + swizzle + DBUF (r12 best) ----------------
// GEMM moratorium: r5 (traffic), r11 (occupancy), r12 (dbuf) all landed within
// noise at ~40us — counters (MfmaUtil 23, VALU 17, HBM 17, conflicts small)
// show no single pipe saturated and the grid caps co-residency at 2 blocks/CU.
// Keep this measured-best form; do not edit without a new counter signal.

__global__ __launch_bounds__(256) void gemm_mfma_dual(
    const unsigned short* __restrict__ Ahi, const unsigned short* __restrict__ Alo,
    const unsigned short* __restrict__ Bhi_l, const unsigned short* __restrict__ Blo_l,
    const unsigned short* __restrict__ Bhi_r, const unsigned short* __restrict__ Blo_r,
    const float* __restrict__ bias_l, const float* __restrict__ bias_r,
    float* __restrict__ Cl, float* __restrict__ Cr)
{
    int bid = blockIdx.x;
    int virt = (bid & 7) * 64 + (bid >> 3);   // bijective: 512 % 8 == 0
    int g  = virt >> 3;        // 0..63  -> bm group (A-panel); 8 per XCD
    int q  = virt & 7;         // 8 sharers of this panel
    int bz = q >> 2;           // 0..1   -> l/r
    int bm = g * 128, bn = (q & 3) * 128;

    const unsigned short* Bhi = bz ? Bhi_r : Bhi_l;
    const unsigned short* Blo = bz ? Blo_r : Blo_l;
    const float* bias         = bz ? bias_r : bias_l;
    float* C                  = bz ? Cr : Cl;

    __shared__ __align__(16) unsigned short lds[2][4 * 128 * 32];   // 2 x 32KB

    int tid = threadIdx.x;
    int wave = tid >> 6, lane = tid & 63;

    const unsigned short* gsrc[4] = {Ahi, Alo, Bhi, Blo};
    int rowbase[4] = {bm, bm, bn, bn};

    const unsigned short* gbase =
        gsrc[wave] + (size_t)(rowbase[wave] + (lane >> 2)) * 512 + (lane & 3) * 8;

    floatx4 acc[4][4] = {};

    int wm = wave & 1, wn = wave >> 1;
    int lr = lane & 15, lq = lane >> 4;

    #pragma unroll
    for (int rg = 0; rg < 8; ++rg) {
        __builtin_amdgcn_global_load_lds(
            (const __attribute__((address_space(1))) unsigned int*)(gbase + (size_t)rg * 16 * 512),
            (__attribute__((address_space(3))) unsigned int*)(&lds[0][wave * 4096 + rg * 512]),
            16, 0, 0);
    }
    __syncthreads();

    for (int it = 0; it < 16; ++it) {
        int cur = it & 1;
        if (it < 15) {
            const unsigned short* g2 = gbase + (it + 1) * 32;
            #pragma unroll
            for (int rg = 0; rg < 8; ++rg) {
                __builtin_amdgcn_global_load_lds(
                    (const __attribute__((address_space(1))) unsigned int*)(g2 + (size_t)rg * 16 * 512),
                    (__attribute__((address_space(3))) unsigned int*)(&lds[cur ^ 1][wave * 4096 + rg * 512]),
                    16, 0, 0);
            }
        }

        bf16x8 ah[4], al[4], bh[4], bl_[4];
        #pragma unroll
        for (int i = 0; i < 4; ++i) {
            int mrow = wm * 64 + i * 16 + lr;
            ah[i]  = *(const bf16x8*)&lds[cur][0 * 4096 + mrow * 32 + lq * 8];
            al[i]  = *(const bf16x8*)&lds[cur][1 * 4096 + mrow * 32 + lq * 8];
            int nrow = wn * 64 + i * 16 + lr;
            bh[i]  = *(const bf16x8*)&lds[cur][2 * 4096 + nrow * 32 + lq * 8];
            bl_[i] = *(const bf16x8*)&lds[cur][3 * 4096 + nrow * 32 + lq * 8];
        }
        #pragma unroll
        for (int i = 0; i < 4; ++i)
            #pragma unroll
            for (int j = 0; j < 4; ++j) {
                acc[i][j] = __builtin_amdgcn_mfma_f32_16x16x32_bf16(ah[i], bh[j],  acc[i][j], 0, 0, 0);
                acc[i][j] = __builtin_amdgcn_mfma_f32_16x16x32_bf16(ah[i], bl_[j], acc[i][j], 0, 0, 0);
                acc[i][j] = __builtin_amdgcn_mfma_f32_16x16x32_bf16(al[i], bh[j],  acc[i][j], 0, 0, 0);
            }

        __syncthreads();
    }

    #pragma unroll
    for (int j = 0; j < 4; ++j) {
        int n = bn + wn * 64 + j * 16 + lr;
        float bv = bias[n];
        #pragma unroll
        for (int i = 0; i < 4; ++i) {
            int mbase = bm + wm * 64 + i * 16 + lq * 4;
            #pragma unroll
            for (int r = 0; r < 4; ++r)
                C[(size_t)(mbase + r) * 512 + n] = acc[i][j][r] + bv;
        }
    }
}

// ---------------- online-softmax aggregation v8 + nt output stores ----------------
// One wave per node. 2-stage pipelined 4-edge stages (r9-measured best form);
// r13: 2-node interleave regressed (+5.7, VGPR-pressure) — reverted.
// r14 single variable: output stores (Ohi/Olo/out) are non-temporal so the
// 2MB/XCD write stream stops evicting the 2MB xl gather slice from L2.
// Loads stay plain-cached (r7: nt loads hurt).

#define DOT8(Xa, Xb, d0, d1)                                              \
    {                                                                     \
        float t_;                                                         \
        t_ = Xa.x + r0.x; d0 = fmaf(av0.x, t_, d0); d1 = fmaf(av0.x, fabsf(t_), d1); \
        t_ = Xa.y + r0.y; d0 = fmaf(av0.y, t_, d0); d1 = fmaf(av0.y, fabsf(t_), d1); \
        t_ = Xa.z + r0.z; d0 = fmaf(av0.z, t_, d0); d1 = fmaf(av0.z, fabsf(t_), d1); \
        t_ = Xa.w + r0.w; d0 = fmaf(av0.w, t_, d0); d1 = fmaf(av0.w, fabsf(t_), d1); \
        t_ = Xb.x + r1.x; d0 = fmaf(av1.x, t_, d0); d1 = fmaf(av1.x, fabsf(t_), d1); \
        t_ = Xb.y + r1.y; d0 = fmaf(av1.y, t_, d0); d1 = fmaf(av1.y, fabsf(t_), d1); \
        t_ = Xb.z + r1.z; d0 = fmaf(av1.z, t_, d0); d1 = fmaf(av1.z, fabsf(t_), d1); \
        t_ = Xb.w + r1.w; d0 = fmaf(av1.w, t_, d0); d1 = fmaf(av1.w, fabsf(t_), d1); \
    }

#define PROCESS4(Xa, Xb, q)                                               \
    {                                                                     \
        float pe[4];                                                      \
        _Pragma("unroll")                                                 \
        for (int k2 = 0; k2 < 4; ++k2) {                                  \
            float d0 = 0.f, d1 = 0.f;                                     \
            DOT8(Xa[k2], Xb[k2], d0, d1);                                 \
            pe[k2] = fmaf(0.6f, d0, 0.4f * d1);                           \
        }                                                                 \
        _Pragma("unroll")                                                 \
        for (int k2 = 0; k2 < 4; ++k2) pe[k2] = wave_sum64(pe[k2]);       \
        float e0 = pe[0];                                                 \
        float e1 = ((q) + 1 < ne) ? pe[1] : -3.0e38f;                     \
        float e2 = ((q) + 2 < ne) ? pe[2] : -3.0e38f;                     \
        float e3 = ((q) + 3 < ne) ? pe[3] : -3.0e38f;                     \
        float bm4 = fmaxf(fmaxf(e0, e1), fmaxf(e2, e3));                  \
        if (bm4 > m) {                                                    \
            float sc = __expf(m - bm4);                                   \
            s *= sc;                                                      \
            acc0.x *= sc; acc0.y *= sc; acc0.z *= sc; acc0.w *= sc;       \
            acc1.x *= sc; acc1.y *= sc; acc1.z *= sc; acc1.w *= sc;       \
            m = bm4;                                                      \
        }                                                                 \
        float w0 = __expf(e0 - m), w1 = __expf(e1 - m);                   \
        float w2 = __expf(e2 - m), w3 = __expf(e3 - m);                   \
        s += (w0 + w1) + (w2 + w3);                                       \
        acc0.x = fmaf(w0, Xa[0].x, fmaf(w1, Xa[1].x, fmaf(w2, Xa[2].x, fmaf(w3, Xa[3].x, acc0.x)))); \
        acc0.y = fmaf(w0, Xa[0].y, fmaf(w1, Xa[1].y, fmaf(w2, Xa[2].y, fmaf(w3, Xa[3].y, acc0.y)))); \
        acc0.z = fmaf(w0, Xa[0].z, fmaf(w1, Xa[1].z, fmaf(w2, Xa[2].z, fmaf(w3, Xa[3].z, acc0.z)))); \
        acc0.w = fmaf(w0, Xa[0].w, fmaf(w1, Xa[1].w, fmaf(w2, Xa[2].w, fmaf(w3, Xa[3].w, acc0.w)))); \
        acc1.x = fmaf(w0, Xb[0].x, fmaf(w1, Xb[1].x, fmaf(w2, Xb[2].x, fmaf(w3, Xb[3].x, acc1.x)))); \
        acc1.y = fmaf(w0, Xb[0].y, fmaf(w1, Xb[1].y, fmaf(w2, Xb[2].y, fmaf(w3, Xb[3].y, acc1.y)))); \
        acc1.z = fmaf(w0, Xb[0].z, fmaf(w1, Xb[1].z, fmaf(w2, Xb[2].z, fmaf(w3, Xb[3].z, acc1.z)))); \
        acc1.w = fmaf(w0, Xb[0].w, fmaf(w1, Xb[1].w, fmaf(w2, Xb[2].w, fmaf(w3, Xb[3].w, acc1.w)))); \
    }

__global__ __launch_bounds__(256, 4) void gat_online(
    const float* __restrict__ xl, const float* __restrict__ xr,
    const float* __restrict__ avec, const float* __restrict__ bias,
    const int* __restrict__ offs, const int* __restrict__ csr_src,
    float* __restrict__ out, unsigned short* __restrict__ Ohi,
    unsigned short* __restrict__ Olo, int write_fp32)
{
    int gid = blockIdx.x;
    int wv = threadIdx.x >> 6, lane = threadIdx.x & 63;
    int node = ((gid & 7) << 10) + ((gid >> 3) << 2) + wv;

    int nb = offs[node], ne = offs[node + 1];

    // indices: stage0 into jA, stage1 into jB (2 stages ahead of compute)
    int jA[4], jB[4];
    int j0 = (nb < ne) ? csr_src[nb] : 0;
    jA[0] = j0;
    #pragma unroll
    for (int k = 1; k < 4; ++k) jA[k] = (nb + k < ne) ? csr_src[nb + k] : j0;
    #pragma unroll
    for (int k = 0; k < 4; ++k) jB[k] = (nb + 4 + k < ne) ? csr_src[nb + 4 + k] : j0;

    size_t loff = (size_t)lane * 8;
    size_t rowoff = (size_t)node * HD + loff;
    float4 r0 = *(const float4*)(xr + rowoff);
    float4 r1 = *(const float4*)(xr + rowoff + 4);
    float4 av0 = *(const float4*)(avec + loff);
    float4 av1 = *(const float4*)(avec + loff + 4);

    float m = -3.0e38f, s = 0.f;
    float4 acc0 = {0.f, 0.f, 0.f, 0.f}, acc1 = {0.f, 0.f, 0.f, 0.f};

    // stage0 data issue (overlaps the xr/avec loads above)
    float4 Aa[4], Ab[4], Ba[4], Bb[4];
    #pragma unroll
    for (int k = 0; k < 4; ++k) {
        const float* xp = xl + (size_t)jA[k] * HD + loff;
        Aa[k] = *(const float4*)xp;
        Ab[k] = *(const float4*)(xp + 4);
    }

    int p = nb;
    if (p < ne) {
        for (;;) {
            // ---- stage using A: issue next-stage data from jB, refill jA 2 ahead
            #pragma unroll
            for (int k = 0; k < 4; ++k) {
                const float* xp = xl + (size_t)jB[k] * HD + loff;
                Ba[k] = *(const float4*)xp;
                Bb[k] = *(const float4*)(xp + 4);
            }
            {
                int p2 = p + 8;
                #pragma unroll
                for (int k = 0; k < 4; ++k)
                    jA[k] = (p2 + k < ne) ? csr_src[p2 + k] : j0;
            }
            PROCESS4(Aa, Ab, p);
            p += 4;
            if (p >= ne) break;

            // ---- stage using B: issue next-stage data from jA, refill jB 2 ahead
            #pragma unroll
            for (int k = 0; k < 4; ++k) {
                const float* xp = xl + (size_t)jA[k] * HD + loff;
                Aa[k] = *(const float4*)xp;
                Ab[k] = *(const float4*)(xp + 4);
            }
            {
                int p2 = p + 8;
                #pragma unroll
                for (int k = 0; k < 4; ++k)
                    jB[k] = (p2 + k < ne) ? csr_src[p2 + k] : j0;
            }
            PROCESS4(Ba, Bb, p);
            p += 4;
            if (p >= ne) break;
        }
    }

    float inv = (s > 0.f) ? 1.f / s : 0.f;   // deg==0 -> out = bias (matches ref)
    float4 b0 = *(const float4*)(bias + loff);
    float4 b1 = *(const float4*)(bias + loff + 4);
    float4 o0, o1;
    o0.x = fmaf(acc0.x, inv, b0.x); o0.y = fmaf(acc0.y, inv, b0.y);
    o0.z = fmaf(acc0.z, inv, b0.z); o0.w = fmaf(acc0.w, inv, b0.w);
    o1.x = fmaf(acc1.x, inv, b1.x); o1.y = fmaf(acc1.y, inv, b1.y);
    o1.z = fmaf(acc1.z, inv, b1.z); o1.w = fmaf(acc1.w, inv, b1.w);

    if (write_fp32) {
        nt_st4(out + rowoff, o0);
        nt_st4(out + rowoff + 4, o1);
    } else {
        ushort4 h, lo;
        h.x = f2bf(o0.x); lo.x = f2bf(o0.x - bf2f(h.x));
        h.y = f2bf(o0.y); lo.y = f2bf(o0.y - bf2f(h.y));
        h.z = f2bf(o0.z); lo.z = f2bf(o0.z - bf2f(h.z));
        h.w = f2bf(o0.w); lo.w = f2bf(o0.w - bf2f(h.w));
        nt_stu4(Ohi + rowoff, h);
        nt_stu4(Olo + rowoff, lo);
        h.x = f2bf(o1.x); lo.x = f2bf(o1.x - bf2f(h.x));
        h.y = f2bf(o1.y); lo.y = f2bf(o1.y - bf2f(h.y));
        h.z = f2bf(o1.z); lo.z = f2bf(o1.z - bf2f(h.z));
        h.w = f2bf(o1.w); lo.w = f2bf(o1.w - bf2f(h.w));
        nt_stu4(Ohi + rowoff + 4, h);
        nt_stu4(Olo + rowoff + 4, lo);
    }
}

// ---------------- launch ----------------

extern "C" void kernel_launch(void* const* d_in, const int* in_sizes, int n_in,
                              void* d_out, int out_size, void* d_ws, size_t ws_size,
                              hipStream_t stream) {
    const float* x0 = (const float*)d_in[0];
    const int* eidx = (const int*)d_in[2];
    int E = in_sizes[2] / 2;
    const int* esrc = eidx;
    const int* edst = eidx + E;

    const float* Wl[3] = {(const float*)d_in[3],  (const float*)d_in[9],  (const float*)d_in[15]};
    const float* bl[3] = {(const float*)d_in[4],  (const float*)d_in[10], (const float*)d_in[16]};
    const float* Wr[3] = {(const float*)d_in[5],  (const float*)d_in[11], (const float*)d_in[17]};
    const float* br[3] = {(const float*)d_in[6],  (const float*)d_in[12], (const float*)d_in[18]};
    const float* av[3] = {(const float*)d_in[7],  (const float*)d_in[13], (const float*)d_in[19]};
    const float* bs[3] = {(const float*)d_in[8],  (const float*)d_in[14], (const float*)d_in[20]};

    char* w = (char*)d_ws;
    unsigned short* Ahi = (unsigned short*)w; w += (size_t)MTOT * HD * 2;
    unsigned short* Alo = (unsigned short*)w; w += (size_t)MTOT * HD * 2;
    unsigned short* wtbase = (unsigned short*)w; w += 12 * (size_t)HD * HD * 2;
    float* xl = (float*)w; w += (size_t)MTOT * HD * 4;
    float* xr = (float*)w; w += (size_t)MTOT * HD * 4;
    int* deg    = (int*)w;
    int* offs   = deg + MTOT;
    int* cursor = offs + MTOT + 8;
    int* csr    = cursor + MTOT;
    const size_t SZ = (size_t)HD * HD;

    prep_convert<<<dim3(16, 16, 8), 256, 0, stream>>>(
        Wl[0], Wr[0], Wl[1], Wr[1], Wl[2], Wr[2], wtbase, x0, Ahi, Alo, deg);
    count_deg<<<(E + 255) / 256, 256, 0, stream>>>(edst, deg, E);
    scan_offsets<<<1, 1024, 0, stream>>>(deg, offs, cursor);
    scatter_edges<<<(E + 255) / 256, 256, 0, stream>>>(esrc, edst, cursor, csr, E);

    for (int L = 0; L < 3; ++L) {
        gemm_mfma_dual<<<512, 256, 0, stream>>>(Ahi, Alo,
            wtbase + (L * 4 + 0) * SZ, wtbase + (L * 4 + 1) * SZ,
            wtbase + (L * 4 + 2) * SZ, wtbase + (L * 4 + 3) * SZ,
            bl[L], br[L], xl, xr);
        int last = (L == 2);
        gat_online<<<MTOT / 4, 256, 0, stream>>>(xl, xr, av[L], bs[L], offs, csr,
                                                 last ? (float*)d_out : nullptr,
                                                 last ? nullptr : Ahi,
                                                 last ? nullptr : Alo,
                                                 last);
    }
}

// Round 15
// 301.429 us; speedup vs baseline: 1.0330x; 1.0006x over previous
//
#include <hip/hip_runtime.h>
#include <math.h>

#define MTOT 8192   // B*N
#define HD   512    // hidden dim

typedef __attribute__((ext_vector_type(8))) short bf16x8;
typedef __attribute__((ext_vector_type(4))) float floatx4;
typedef __attribute__((ext_vector_type(4))) float f32x4;
typedef __attribute__((ext_vector_type(4))) unsigned short u16x4;

__device__ inline unsigned short f2bf(float f) {
    unsigned int u = __float_as_uint(f);
    unsigned int r = (u + 0x7FFFu + ((u >> 16) & 1u)) >> 16;
    return (unsigned short)r;
}
__device__ inline float bf2f(unsigned short h) {
    return __uint_as_float(((unsigned int)h) << 16);
}

// non-temporal helpers. Caching-policy ledger (all individually measured):
//   stores (Ohi/Olo/out): nt GOOD (-4us, r14) — write stream was evicting xl.
//   csr idx loads:        nt BAD  (r7 bundle; repeated + latency-critical).
//   xr row loads:         nt ??? (r15 single-variable test — zero-reuse
//                         stream, last remaining L2 evictor of the xl slice).
//   xl/avec/bias:         plain (reused; xl residency is the whole game).
__device__ inline void nt_st4(float* p, float4 v) {
    f32x4 t = {v.x, v.y, v.z, v.w};
    __builtin_nontemporal_store(t, (f32x4*)p);
}
__device__ inline void nt_stu4(unsigned short* p, ushort4 v) {
    u16x4 t = {v.x, v.y, v.z, v.w};
    __builtin_nontemporal_store(t, (u16x4*)p);
}
__device__ inline float4 nt_ld4(const float* p) {
    f32x4 v = __builtin_nontemporal_load((const f32x4*)p);
    return make_float4(v.x, v.y, v.z, v.w);
}

// wave-wide sum: 4 DPP row_ror adds (VALU pipe, row=16 lanes) + 2 shfl_xor
// (LDS pipe) for the cross-row levels. Replaces 6 dependent ds_bpermute.
__device__ inline float wave_sum64(float v) {
    int t;
    t = __builtin_amdgcn_update_dpp(0, __float_as_int(v), 0x121, 0xF, 0xF, true); v += __int_as_float(t); // row_ror:1
    t = __builtin_amdgcn_update_dpp(0, __float_as_int(v), 0x122, 0xF, 0xF, true); v += __int_as_float(t); // row_ror:2
    t = __builtin_amdgcn_update_dpp(0, __float_as_int(v), 0x124, 0xF, 0xF, true); v += __int_as_float(t); // row_ror:4
    t = __builtin_amdgcn_update_dpp(0, __float_as_int(v), 0x128, 0xF, 0xF, true); v += __int_as_float(t); // row_ror:8
    v += __shfl_xor(v, 16, 64);
    v += __shfl_xor(v, 32, 64);
    return v;
}

// ---------------- CSR build (separate dispatches — r8: fusing count into the
// GEMM cost +9us via L2 atomic contention; no grid.sync re-fusion (~35us).
// Fusing count into prep nets zero: deg must be re-zeroed after the harness's
// per-iteration workspace poison, so it would just trade a kernel for a memset.

__global__ void count_deg(const int* __restrict__ dst, int* __restrict__ deg, int E) {
    int i = blockIdx.x * 256 + threadIdx.x;
    if (i < E) atomicAdd(&deg[dst[i]], 1);
}

__global__ __launch_bounds__(1024) void scan_offsets(const int* __restrict__ deg,
                                                     int* __restrict__ offs,
                                                     int* __restrict__ cursor) {
    __shared__ int part[1024];
    int tid = threadIdx.x;
    int base = tid * 8;
    int v[8]; int s = 0;
    #pragma unroll
    for (int i = 0; i < 8; ++i) { v[i] = deg[base + i]; s += v[i]; }
    part[tid] = s;
    __syncthreads();
    for (int off = 1; off < 1024; off <<= 1) {
        int t = (tid >= off) ? part[tid - off] : 0;
        __syncthreads();
        part[tid] += t;
        __syncthreads();
    }
    int run = (tid == 0) ? 0 : part[tid - 1];
    #pragma unroll
    for (int i = 0; i < 8; ++i) {
        offs[base + i] = run;
        cursor[base + i] = run;
        run += v[i];
    }
    if (tid == 1023) offs[MTOT] = run;
}

__global__ void scatter_edges(const int* __restrict__ src, const int* __restrict__ dst,
                              int* __restrict__ cursor, int* __restrict__ csr_src, int E) {
    int i = blockIdx.x * 256 + threadIdx.x;
    if (i < E) {
        int p = atomicAdd(&cursor[dst[i]], 1);
        csr_src[p] = src[i];
    }
}

// ---------------- combined weight + activation split + deg zero ----------------
// z in [0,6): weight matrix z. z == 6: activation split. z == 7: zero deg.

__global__ __launch_bounds__(256) void prep_convert(
    const float* __restrict__ W0, const float* __restrict__ W1,
    const float* __restrict__ W2, const float* __restrict__ W3,
    const float* __restrict__ W4, const float* __restrict__ W5,
    unsigned short* __restrict__ wtbase,
    const float* __restrict__ X,
    unsigned short* __restrict__ Ahi, unsigned short* __restrict__ Alo,
    int* __restrict__ deg)
{
    int z = blockIdx.z;
    if (z == 7) {
        if (blockIdx.x == 0 && blockIdx.y == 0)
            for (int i = threadIdx.x; i < MTOT; i += 256) deg[i] = 0;
        return;
    }
    if (z == 6) {
        int bid = blockIdx.x * 16 + blockIdx.y;       // 0..255
        int t0 = bid * 256 + threadIdx.x;             // 0..65535
        #pragma unroll
        for (int it = 0; it < 16; ++it) {
            int i = (t0 + it * 65536) * 4;
            float4 vv = *(const float4*)(X + i);
            ushort4 h, l;
            h.x = f2bf(vv.x); l.x = f2bf(vv.x - bf2f(h.x));
            h.y = f2bf(vv.y); l.y = f2bf(vv.y - bf2f(h.y));
            h.z = f2bf(vv.z); l.z = f2bf(vv.z - bf2f(h.z));
            h.w = f2bf(vv.w); l.w = f2bf(vv.w - bf2f(h.w));
            *(ushort4*)(Ahi + i) = h;
            *(ushort4*)(Alo + i) = l;
        }
        return;
    }
    const float* W = (z == 0) ? W0 : (z == 1) ? W1 : (z == 2) ? W2
                   : (z == 3) ? W3 : (z == 4) ? W4 : W5;
    int L = z >> 1, lr = z & 1;
    const size_t SZ = (size_t)HD * HD;
    unsigned short* Whi = wtbase + (L * 4 + lr * 2) * SZ;
    unsigned short* Wlo = Whi + SZ;

    __shared__ float t[32][33];
    int bx = blockIdx.x * 32;  // n base
    int by = blockIdx.y * 32;  // k base
    int tx = threadIdx.x & 31, ty = threadIdx.x >> 5;
    for (int i = ty; i < 32; i += 8)
        t[i][tx] = W[(size_t)(by + i) * HD + bx + tx];
    __syncthreads();
    for (int i = ty; i < 32; i += 8) {
        float vv = t[tx][i];
        unsigned short h = f2bf(vv);
        unsigned short l = f2bf(vv - bf2f(h));
        Whi[(size_t)(bx + i) * HD + by + tx] = h;
        Wlo[(size_t)(bx + i) * HD + by + tx] = l;
    }
}

// ---------------- split-bf16 MFMA dual GEMM, 128x128 + swizzle + DBUF (r12 best) ----------------
// GEMM moratorium: r5 (traffic), r11 (occupancy), r12 (dbuf) all landed within
// noise at ~40us — counters (MfmaUtil 23, VALU 17, HBM 17, conflicts small)
// show no single pipe saturated and the grid caps co-residency at 2 blocks/CU.
// Keep this measured-best form; do not edit without a new counter signal.
// C-writes stay PLAIN (cross-kernel: agg may L2-hit the xl/xr lines; the
// same-XCD alignment holds under this swizzle).

__global__ __launch_bounds__(256) void gemm_mfma_dual(
    const unsigned short* __restrict__ Ahi, const unsigned short* __restrict__ Alo,
    const unsigned short* __restrict__ Bhi_l, const unsigned short* __restrict__ Blo_l,
    const unsigned short* __restrict__ Bhi_r, const unsigned short* __restrict__ Blo_r,
    const float* __restrict__ bias_l, const float* __restrict__ bias_r,
    float* __restrict__ Cl, float* __restrict__ Cr)
{
    int bid = blockIdx.x;
    int virt = (bid & 7) * 64 + (bid >> 3);   // bijective: 512 % 8 == 0
    int g  = virt >> 3;        // 0..63  -> bm group (A-panel); 8 per XCD
    int q  = virt & 7;         // 8 sharers of this panel
    int bz = q >> 2;           // 0..1   -> l/r
    int bm = g * 128, bn = (q & 3) * 128;

    const unsigned short* Bhi = bz ? Bhi_r : Bhi_l;
    const unsigned short* Blo = bz ? Blo_r : Blo_l;
    const float* bias         = bz ? bias_r : bias_l;
    float* C                  = bz ? Cr : Cl;

    __shared__ __align__(16) unsigned short lds[2][4 * 128 * 32];   // 2 x 32KB

    int tid = threadIdx.x;
    int wave = tid >> 6, lane = tid & 63;

    const unsigned short* gsrc[4] = {Ahi, Alo, Bhi, Blo};
    int rowbase[4] = {bm, bm, bn, bn};

    const unsigned short* gbase =
        gsrc[wave] + (size_t)(rowbase[wave] + (lane >> 2)) * 512 + (lane & 3) * 8;

    floatx4 acc[4][4] = {};

    int wm = wave & 1, wn = wave >> 1;
    int lr = lane & 15, lq = lane >> 4;

    #pragma unroll
    for (int rg = 0; rg < 8; ++rg) {
        __builtin_amdgcn_global_load_lds(
            (const __attribute__((address_space(1))) unsigned int*)(gbase + (size_t)rg * 16 * 512),
            (__attribute__((address_space(3))) unsigned int*)(&lds[0][wave * 4096 + rg * 512]),
            16, 0, 0);
    }
    __syncthreads();

    for (int it = 0; it < 16; ++it) {
        int cur = it & 1;
        if (it < 15) {
            const unsigned short* g2 = gbase + (it + 1) * 32;
            #pragma unroll
            for (int rg = 0; rg < 8; ++rg) {
                __builtin_amdgcn_global_load_lds(
                    (const __attribute__((address_space(1))) unsigned int*)(g2 + (size_t)rg * 16 * 512),
                    (__attribute__((address_space(3))) unsigned int*)(&lds[cur ^ 1][wave * 4096 + rg * 512]),
                    16, 0, 0);
            }
        }

        bf16x8 ah[4], al[4], bh[4], bl_[4];
        #pragma unroll
        for (int i = 0; i < 4; ++i) {
            int mrow = wm * 64 + i * 16 + lr;
            ah[i]  = *(const bf16x8*)&lds[cur][0 * 4096 + mrow * 32 + lq * 8];
            al[i]  = *(const bf16x8*)&lds[cur][1 * 4096 + mrow * 32 + lq * 8];
            int nrow = wn * 64 + i * 16 + lr;
            bh[i]  = *(const bf16x8*)&lds[cur][2 * 4096 + nrow * 32 + lq * 8];
            bl_[i] = *(const bf16x8*)&lds[cur][3 * 4096 + nrow * 32 + lq * 8];
        }
        #pragma unroll
        for (int i = 0; i < 4; ++i)
            #pragma unroll
            for (int j = 0; j < 4; ++j) {
                acc[i][j] = __builtin_amdgcn_mfma_f32_16x16x32_bf16(ah[i], bh[j],  acc[i][j], 0, 0, 0);
                acc[i][j] = __builtin_amdgcn_mfma_f32_16x16x32_bf16(ah[i], bl_[j], acc[i][j], 0, 0, 0);
                acc[i][j] = __builtin_amdgcn_mfma_f32_16x16x32_bf16(al[i], bh[j],  acc[i][j], 0, 0, 0);
            }

        __syncthreads();
    }

    #pragma unroll
    for (int j = 0; j < 4; ++j) {
        int n = bn + wn * 64 + j * 16 + lr;
        float bv = bias[n];
        #pragma unroll
        for (int i = 0; i < 4; ++i) {
            int mbase = bm + wm * 64 + i * 16 + lq * 4;
            #pragma unroll
            for (int r = 0; r < 4; ++r)
                C[(size_t)(mbase + r) * 512 + n] = acc[i][j][r] + bv;
        }
    }
}

// ---------------- online-softmax aggregation v8 + nt stores + nt xr loads ----------------
// One wave per node. 2-stage pipelined 4-edge stages (r9-measured best form).
// r14: nt output stores -4us (pollution mechanism confirmed). r15 single
// variable: xr row loads nt — xr is zero-reuse (one row per wave) and, with
// stores already nt, is the LAST remaining evictor of the 2MB/XCD xl gather
// slice (xr 2MB + xl 2MB = exactly L2 capacity). csr idx / xl / avec / bias
// stay plain-cached (reused or latency-critical).

#define DOT8(Xa, Xb, d0, d1)                                              \
    {                                                                     \
        float t_;                                                         \
        t_ = Xa.x + r0.x; d0 = fmaf(av0.x, t_, d0); d1 = fmaf(av0.x, fabsf(t_), d1); \
        t_ = Xa.y + r0.y; d0 = fmaf(av0.y, t_, d0); d1 = fmaf(av0.y, fabsf(t_), d1); \
        t_ = Xa.z + r0.z; d0 = fmaf(av0.z, t_, d0); d1 = fmaf(av0.z, fabsf(t_), d1); \
        t_ = Xa.w + r0.w; d0 = fmaf(av0.w, t_, d0); d1 = fmaf(av0.w, fabsf(t_), d1); \
        t_ = Xb.x + r1.x; d0 = fmaf(av1.x, t_, d0); d1 = fmaf(av1.x, fabsf(t_), d1); \
        t_ = Xb.y + r1.y; d0 = fmaf(av1.y, t_, d0); d1 = fmaf(av1.y, fabsf(t_), d1); \
        t_ = Xb.z + r1.z; d0 = fmaf(av1.z, t_, d0); d1 = fmaf(av1.z, fabsf(t_), d1); \
        t_ = Xb.w + r1.w; d0 = fmaf(av1.w, t_, d0); d1 = fmaf(av1.w, fabsf(t_), d1); \
    }

#define PROCESS4(Xa, Xb, q)                                               \
    {                                                                     \
        float pe[4];                                                      \
        _Pragma("unroll")                                                 \
        for (int k2 = 0; k2 < 4; ++k2) {                                  \
            float d0 = 0.f, d1 = 0.f;                                     \
            DOT8(Xa[k2], Xb[k2], d0, d1);                                 \
            pe[k2] = fmaf(0.6f, d0, 0.4f * d1);                           \
        }                                                                 \
        _Pragma("unroll")                                                 \
        for (int k2 = 0; k2 < 4; ++k2) pe[k2] = wave_sum64(pe[k2]);       \
        float e0 = pe[0];                                                 \
        float e1 = ((q) + 1 < ne) ? pe[1] : -3.0e38f;                     \
        float e2 = ((q) + 2 < ne) ? pe[2] : -3.0e38f;                     \
        float e3 = ((q) + 3 < ne) ? pe[3] : -3.0e38f;                     \
        float bm4 = fmaxf(fmaxf(e0, e1), fmaxf(e2, e3));                  \
        if (bm4 > m) {                                                    \
            float sc = __expf(m - bm4);                                   \
            s *= sc;                                                      \
            acc0.x *= sc; acc0.y *= sc; acc0.z *= sc; acc0.w *= sc;       \
            acc1.x *= sc; acc1.y *= sc; acc1.z *= sc; acc1.w *= sc;       \
            m = bm4;                                                      \
        }                                                                 \
        float w0 = __expf(e0 - m), w1 = __expf(e1 - m);                   \
        float w2 = __expf(e2 - m), w3 = __expf(e3 - m);                   \
        s += (w0 + w1) + (w2 + w3);                                       \
        acc0.x = fmaf(w0, Xa[0].x, fmaf(w1, Xa[1].x, fmaf(w2, Xa[2].x, fmaf(w3, Xa[3].x, acc0.x)))); \
        acc0.y = fmaf(w0, Xa[0].y, fmaf(w1, Xa[1].y, fmaf(w2, Xa[2].y, fmaf(w3, Xa[3].y, acc0.y)))); \
        acc0.z = fmaf(w0, Xa[0].z, fmaf(w1, Xa[1].z, fmaf(w2, Xa[2].z, fmaf(w3, Xa[3].z, acc0.z)))); \
        acc0.w = fmaf(w0, Xa[0].w, fmaf(w1, Xa[1].w, fmaf(w2, Xa[2].w, fmaf(w3, Xa[3].w, acc0.w)))); \
        acc1.x = fmaf(w0, Xb[0].x, fmaf(w1, Xb[1].x, fmaf(w2, Xb[2].x, fmaf(w3, Xb[3].x, acc1.x)))); \
        acc1.y = fmaf(w0, Xb[0].y, fmaf(w1, Xb[1].y, fmaf(w2, Xb[2].y, fmaf(w3, Xb[3].y, acc1.y)))); \
        acc1.z = fmaf(w0, Xb[0].z, fmaf(w1, Xb[1].z, fmaf(w2, Xb[2].z, fmaf(w3, Xb[3].z, acc1.z)))); \
        acc1.w = fmaf(w0, Xb[0].w, fmaf(w1, Xb[1].w, fmaf(w2, Xb[2].w, fmaf(w3, Xb[3].w, acc1.w)))); \
    }

__global__ __launch_bounds__(256, 4) void gat_online(
    const float* __restrict__ xl, const float* __restrict__ xr,
    const float* __restrict__ avec, const float* __restrict__ bias,
    const int* __restrict__ offs, const int* __restrict__ csr_src,
    float* __restrict__ out, unsigned short* __restrict__ Ohi,
    unsigned short* __restrict__ Olo, int write_fp32)
{
    int gid = blockIdx.x;
    int wv = threadIdx.x >> 6, lane = threadIdx.x & 63;
    int node = ((gid & 7) << 10) + ((gid >> 3) << 2) + wv;

    int nb = offs[node], ne = offs[node + 1];

    // indices: stage0 into jA, stage1 into jB (2 stages ahead of compute)
    int jA[4], jB[4];
    int j0 = (nb < ne) ? csr_src[nb] : 0;
    jA[0] = j0;
    #pragma unroll
    for (int k = 1; k < 4; ++k) jA[k] = (nb + k < ne) ? csr_src[nb + k] : j0;
    #pragma unroll
    for (int k = 0; k < 4; ++k) jB[k] = (nb + 4 + k < ne) ? csr_src[nb + 4 + k] : j0;

    size_t loff = (size_t)lane * 8;
    size_t rowoff = (size_t)node * HD + loff;
    float4 r0 = nt_ld4(xr + rowoff);          // r15: nt — zero-reuse stream
    float4 r1 = nt_ld4(xr + rowoff + 4);
    float4 av0 = *(const float4*)(avec + loff);
    float4 av1 = *(const float4*)(avec + loff + 4);

    float m = -3.0e38f, s = 0.f;
    float4 acc0 = {0.f, 0.f, 0.f, 0.f}, acc1 = {0.f, 0.f, 0.f, 0.f};

    // stage0 data issue (overlaps the xr/avec loads above)
    float4 Aa[4], Ab[4], Ba[4], Bb[4];
    #pragma unroll
    for (int k = 0; k < 4; ++k) {
        const float* xp = xl + (size_t)jA[k] * HD + loff;
        Aa[k] = *(const float4*)xp;
        Ab[k] = *(const float4*)(xp + 4);
    }

    int p = nb;
    if (p < ne) {
        for (;;) {
            // ---- stage using A: issue next-stage data from jB, refill jA 2 ahead
            #pragma unroll
            for (int k = 0; k < 4; ++k) {
                const float* xp = xl + (size_t)jB[k] * HD + loff;
                Ba[k] = *(const float4*)xp;
                Bb[k] = *(const float4*)(xp + 4);
            }
            {
                int p2 = p + 8;
                #pragma unroll
                for (int k = 0; k < 4; ++k)
                    jA[k] = (p2 + k < ne) ? csr_src[p2 + k] : j0;
            }
            PROCESS4(Aa, Ab, p);
            p += 4;
            if (p >= ne) break;

            // ---- stage using B: issue next-stage data from jA, refill jB 2 ahead
            #pragma unroll
            for (int k = 0; k < 4; ++k) {
                const float* xp = xl + (size_t)jA[k] * HD + loff;
                Aa[k] = *(const float4*)xp;
                Ab[k] = *(const float4*)(xp + 4);
            }
            {
                int p2 = p + 8;
                #pragma unroll
                for (int k = 0; k < 4; ++k)
                    jB[k] = (p2 + k < ne) ? csr_src[p2 + k] : j0;
            }
            PROCESS4(Ba, Bb, p);
            p += 4;
            if (p >= ne) break;
        }
    }

    float inv = (s > 0.f) ? 1.f / s : 0.f;   // deg==0 -> out = bias (matches ref)
    float4 b0 = *(const float4*)(bias + loff);
    float4 b1 = *(const float4*)(bias + loff + 4);
    float4 o0, o1;
    o0.x = fmaf(acc0.x, inv, b0.x); o0.y = fmaf(acc0.y, inv, b0.y);
    o0.z = fmaf(acc0.z, inv, b0.z); o0.w = fmaf(acc0.w, inv, b0.w);
    o1.x = fmaf(acc1.x, inv, b1.x); o1.y = fmaf(acc1.y, inv, b1.y);
    o1.z = fmaf(acc1.z, inv, b1.z); o1.w = fmaf(acc1.w, inv, b1.w);

    if (write_fp32) {
        nt_st4(out + rowoff, o0);
        nt_st4(out + rowoff + 4, o1);
    } else {
        ushort4 h, lo;
        h.x = f2bf(o0.x); lo.x = f2bf(o0.x - bf2f(h.x));
        h.y = f2bf(o0.y); lo.y = f2bf(o0.y - bf2f(h.y));
        h.z = f2bf(o0.z); lo.z = f2bf(o0.z - bf2f(h.z));
        h.w = f2bf(o0.w); lo.w = f2bf(o0.w - bf2f(h.w));
        nt_stu4(Ohi + rowoff, h);
        nt_stu4(Olo + rowoff, lo);
        h.x = f2bf(o1.x); lo.x = f2bf(o1.x - bf2f(h.x));
        h.y = f2bf(o1.y); lo.y = f2bf(o1.y - bf2f(h.y));
        h.z = f2bf(o1.z); lo.z = f2bf(o1.z - bf2f(h.z));
        h.w = f2bf(o1.w); lo.w = f2bf(o1.w - bf2f(h.w));
        nt_stu4(Ohi + rowoff + 4, h);
        nt_stu4(Olo + rowoff + 4, lo);
    }
}

// ---------------- launch ----------------

extern "C" void kernel_launch(void* const* d_in, const int* in_sizes, int n_in,
                              void* d_out, int out_size, void* d_ws, size_t ws_size,
                              hipStream_t stream) {
    const float* x0 = (const float*)d_in[0];
    const int* eidx = (const int*)d_in[2];
    int E = in_sizes[2] / 2;
    const int* esrc = eidx;
    const int* edst = eidx + E;

    const float* Wl[3] = {(const float*)d_in[3],  (const float*)d_in[9],  (const float*)d_in[15]};
    const float* bl[3] = {(const float*)d_in[4],  (const float*)d_in[10], (const float*)d_in[16]};
    const float* Wr[3] = {(const float*)d_in[5],  (const float*)d_in[11], (const float*)d_in[17]};
    const float* br[3] = {(const float*)d_in[6],  (const float*)d_in[12], (const float*)d_in[18]};
    const float* av[3] = {(const float*)d_in[7],  (const float*)d_in[13], (const float*)d_in[19]};
    const float* bs[3] = {(const float*)d_in[8],  (const float*)d_in[14], (const float*)d_in[20]};

    char* w = (char*)d_ws;
    unsigned short* Ahi = (unsigned short*)w; w += (size_t)MTOT * HD * 2;
    unsigned short* Alo = (unsigned short*)w; w += (size_t)MTOT * HD * 2;
    unsigned short* wtbase = (unsigned short*)w; w += 12 * (size_t)HD * HD * 2;
    float* xl = (float*)w; w += (size_t)MTOT * HD * 4;
    float* xr = (float*)w; w += (size_t)MTOT * HD * 4;
    int* deg    = (int*)w;
    int* offs   = deg + MTOT;
    int* cursor = offs + MTOT + 8;
    int* csr    = cursor + MTOT;
    const size_t SZ = (size_t)HD * HD;

    prep_convert<<<dim3(16, 16, 8), 256, 0, stream>>>(
        Wl[0], Wr[0], Wl[1], Wr[1], Wl[2], Wr[2], wtbase, x0, Ahi, Alo, deg);
    count_deg<<<(E + 255) / 256, 256, 0, stream>>>(edst, deg, E);
    scan_offsets<<<1, 1024, 0, stream>>>(deg, offs, cursor);
    scatter_edges<<<(E + 255) / 256, 256, 0, stream>>>(esrc, edst, cursor, csr, E);

    for (int L = 0; L < 3; ++L) {
        gemm_mfma_dual<<<512, 256, 0, stream>>>(Ahi, Alo,
            wtbase + (L * 4 + 0) * SZ, wtbase + (L * 4 + 1) * SZ,
            wtbase + (L * 4 + 2) * SZ, wtbase + (L * 4 + 3) * SZ,
            bl[L], br[L], xl, xr);
        int last = (L == 2);
        gat_online<<<MTOT / 4, 256, 0, stream>>>(xl, xr, av[L], bs[L], offs, csr,
                                                 last ? (float*)d_out : nullptr,
                                                 last ? nullptr : Ahi,
                                                 last ? nullptr : Alo,
                                                 last);
    }
}